// Round 9
// baseline (241.859 us; speedup 1.0000x reference)
//
#include <hip/hip_runtime.h>
#include <stdint.h>

// DetectionBaseline: SSD post-process. R9: per-batch IoU>0.45 BIT MATRIX precomputed
// once (shared by all 20 classes — removes the 20x redundant IoU compute that dominated
// P1). chunk_nms P1/P2 become bit lookups. R8 chunk kernel kept verbatim as ws fallback.
//   prep      : per (b,a) box decode + softmax (m,sum)
//   iou       : per b, 1280x1280 IoU bit matrix (20 u64 words/row)
//   sort      : per (b,c) key build + register bitonic sort -> u16 rank list
//   chunk_iou : per (b,c) chunked greedy NMS via bit lookups -> kept key lists
//   merge     : per b truncated pairwise bitonic merges -> top-200 output

#define A_N     1280
#define CF      20
#define NC      21
#define B_N     16
#define TOPK    200
#define THREADS 256
#define CTHREADS 512
#define SORT_N  2048
#define CH      128
#define IOU_WPR (A_N / 64)   // 20 u64 words per matrix row

// ws layout (bytes)
#define KEYS_BYTES   (B_N * CF * TOPK * 8)                 // 512000 kept-key lists
#define BOX_OFF      KEYS_BYTES                             // float4 [16*1280] = 327680
#define MS_OFF       (BOX_OFF + B_N * A_N * 16)             // float2 [16*1280] = 163840
#define RANKS_OFF    (MS_OFF + B_N * A_N * 8)               // u16 [320*1280]   = 819200
#define WS_B_BYTES   RANKS_OFF                              // 1003520 (mono-prep tier)
#define WS_A_BYTES   (RANKS_OFF + (size_t)B_N * CF * A_N * 2)  // 1822720 (R8 tier)
#define IOU_OFF      WS_A_BYTES                              // u64 [16][1280][20]
#define WS_C_BYTES   (IOU_OFF + (size_t)B_N * A_N * IOU_WPR * 8)  // 5099520 (bit-matrix tier)

static __device__ __forceinline__ uint64_t pack_key(float sc, uint32_t idx) {
    // softmax scores positive -> float bits monotone. ~bits => ascending key = descending
    // score; low 32 bits = index => ties break toward smaller index (stable argsort / top_k).
    return ((uint64_t)(uint32_t)(~__float_as_uint(sc)) << 32) | (uint64_t)idx;
}

static __device__ __forceinline__ float box_area(const float4 v) {
    return (v.z - v.x) * (v.w - v.y);
}

static __device__ __forceinline__ bool iou_gt(const float4 a, const float aarea,
                                              const float4 b, const float barea) {
    // ref-exact: inter/(area_a + area_b - inter) > 0.45; exactly symmetric in IEEE
    const float lx = fmaxf(a.x, b.x);
    const float ly = fmaxf(a.y, b.y);
    const float rx = fminf(a.z, b.z);
    const float ry = fminf(a.w, b.w);
    const float wx = fmaxf(rx - lx, 0.0f);
    const float wy = fmaxf(ry - ly, 0.0f);
    const float inter = wx * wy;
    const float uni   = aarea + barea - inter;
    return inter / uni > 0.45f;
}

static __device__ __forceinline__ float4 decode_box(const float4 lc, const float4 an) {
    const float cx = lc.x * an.z / 10.0f + an.x;
    const float cy = lc.y * an.w / 10.0f + an.y;
    const float w  = expf(lc.z / 5.0f) * an.z;
    const float h  = expf(lc.w / 5.0f) * an.w;
    float4 v;
    v.x = cx - w / 2.0f; v.y = cy - h / 2.0f;
    v.z = cx + w / 2.0f; v.w = cy + h / 2.0f;
    return v;
}

static __device__ __forceinline__ float4 shfl_box(const float4 v, int lane) {
    float4 r;
    r.x = __shfl(v.x, lane, 64);
    r.y = __shfl(v.y, lane, 64);
    r.z = __shfl(v.z, lane, 64);
    r.w = __shfl(v.w, lane, 64);
    return r;
}

static __device__ __forceinline__ uint64_t readlane_u64(uint64_t v, int lane) {
    const uint32_t lo = (uint32_t)__builtin_amdgcn_readlane((int)(uint32_t)v, lane);
    const uint32_t hi = (uint32_t)__builtin_amdgcn_readlane((int)(uint32_t)(v >> 32), lane);
    return ((uint64_t)hi << 32) | lo;
}

// ---- prep: per (b,a) decoded box + softmax (max, sum) ----
__global__ __launch_bounds__(THREADS)
void prep_kernel(const float* __restrict__ locs,
                 const float* __restrict__ scores,
                 const float* __restrict__ anchors,
                 float4* __restrict__ boxes_ws,
                 float2* __restrict__ ms_ws)
{
    const int g = blockIdx.x * THREADS + threadIdx.x;
    if (g >= B_N * A_N) return;
    const int a = g % A_N;
    boxes_ws[g] = decode_box(((const float4*)locs)[g], ((const float4*)anchors)[a]);
    const float* sp = scores + (size_t)g * NC;
    float m = sp[0];
    #pragma unroll
    for (int k = 1; k < NC; ++k) m = fmaxf(m, sp[k]);
    float sum = 0.0f;
    #pragma unroll
    for (int k = 0; k < NC; ++k) sum += expf(sp[k] - m);
    ms_ws[g] = make_float2(m, sum);
}

// ---- iou: per-batch 1280x1280 bit matrix; wave = (b, colword, 128-row slice) ----
__global__ __launch_bounds__(THREADS)
void iou_kernel(const float4* __restrict__ boxes_ws,
                uint64_t* __restrict__ iou_ws)
{
    const int t  = threadIdx.x, l = t & 63, w = t >> 6;
    const int gw = blockIdx.x * (THREADS / 64) + w;   // 0..3199
    const int rs = gw % 10;                            // row slice (128 rows)
    const int cw = (gw / 10) % IOU_WPR;                // col word
    const int b  = gw / (10 * IOU_WPR);
    const float4* const bb = boxes_ws + (size_t)b * A_N;
    const float4 cbx = bb[cw * 64 + l];
    const float  ca  = box_area(cbx);
    uint64_t* const obase = iou_ws + (size_t)b * A_N * IOU_WPR + cw;
    const int r0 = rs * 128;
    for (int r = r0; r < r0 + 128; ++r) {
        const float4 rbx = bb[r];                     // uniform (L1 broadcast)
        const float  ra  = box_area(rbx);
        const uint64_t m = __ballot(iou_gt(rbx, ra, cbx, ca));
        if (l == 0) obase[(size_t)r * IOU_WPR] = m;
    }
}

// ---- sort: per (b,c) build keys, register bitonic sort, emit u16 rank list ----
__global__ __launch_bounds__(THREADS)
void sort_kernel(const float* __restrict__ scores,
                 const float2* __restrict__ ms_ws,
                 unsigned short* __restrict__ ranks_ws)
{
    __shared__ uint64_t skeys[SORT_N];   // 16 KB

    const int blk = blockIdx.x;
    const int b   = blk / CF;
    const int c   = blk % CF + 1;
    const int t   = threadIdx.x;
    const int l   = t & 63;
    const int w   = t >> 6;

    #pragma unroll
    for (int i = 0; i < A_N / THREADS; ++i) {
        const int a = t + i * THREADS;
        const float2 ms = ms_ws[b * A_N + a];
        const float  sl = scores[((size_t)b * A_N + a) * NC + c];
        const float  sc = expf(sl - ms.x) / ms.y;          // ref-exact softmax value
        skeys[a] = (sc > 0.01f) ? pack_key(sc, (uint32_t)a) : ~0ull;
    }
    for (int i = A_N + t; i < SORT_N; i += THREADS) skeys[i] = ~0ull;
    __syncthreads();

    // register/wave bitonic sort, element e = w*512 + r*64 + l (R4..R8-verified)
    uint64_t k[8];
    #pragma unroll
    for (int r = 0; r < 8; ++r) k[r] = skeys[(w << 9) + (r << 6) + l];

    for (int kk = 2; kk <= SORT_N; kk <<= 1) {
        for (int j = kk >> 1; j; j >>= 1) {
            if (j >= 512) {
                __syncthreads();
                #pragma unroll
                for (int r = 0; r < 8; ++r) skeys[(w << 9) + (r << 6) + l] = k[r];
                __syncthreads();
                #pragma unroll
                for (int r = 0; r < 8; ++r) {
                    const int e = (w << 9) + (r << 6) + l;
                    const uint64_t o = skeys[e ^ j];
                    const bool keep_min = (((e & j) == 0) == ((e & kk) == 0));
                    const uint64_t mn = k[r] < o ? k[r] : o;
                    const uint64_t mx = k[r] < o ? o : k[r];
                    k[r] = keep_min ? mn : mx;
                }
            } else if (j >= 64) {
                const int rb = j >> 6;
                #pragma unroll
                for (int r = 0; r < 8; ++r) {
                    if ((r & rb) == 0) {
                        const int p = r | rb;
                        const int e = (w << 9) + (r << 6) + l;
                        const bool up = ((e & kk) == 0);
                        const uint64_t x = k[r], y = k[p];
                        const uint64_t mn = x < y ? x : y;
                        const uint64_t mx = x < y ? y : x;
                        k[r] = up ? mn : mx;
                        k[p] = up ? mx : mn;
                    }
                }
            } else {
                #pragma unroll
                for (int r = 0; r < 8; ++r) {
                    const uint64_t o = (uint64_t)__shfl_xor((unsigned long long)k[r], j, 64);
                    const int e = (w << 9) + (r << 6) + l;
                    const bool keep_min = (((e & j) == 0) == ((e & kk) == 0));
                    const uint64_t mn = k[r] < o ? k[r] : o;
                    const uint64_t mx = k[r] < o ? o : k[r];
                    k[r] = keep_min ? mn : mx;
                }
            }
        }
    }
    // valid candidates <= 1280 -> ranks >= 1280 all-invalid: store first 1280 only
    unsigned short* const dst = ranks_ws + (size_t)blk * A_N;
    #pragma unroll
    for (int r = 0; r < 8; ++r) {
        const int e = (w << 9) + (r << 6) + l;
        if (e < A_N)
            dst[e] = (k[r] == ~0ull) ? (unsigned short)0xFFFF
                                     : (unsigned short)(k[r] & 0xFFFF);
    }
}

// ---- chunk_iou (512 threads): greedy NMS, all IoU tests are bit-matrix lookups ----
__global__ __launch_bounds__(CTHREADS)
void chunk_nms_iou_kernel(const float* __restrict__ scores,
                          const float2* __restrict__ ms_ws,
                          const unsigned short* __restrict__ ranks_ws,
                          const uint64_t* __restrict__ iou_ws,
                          uint64_t* __restrict__ ws_keys)
{
    __shared__ unsigned short sranks[A_N];    // 2.5 KB
    __shared__ uint64_t       srow[CH][2];    // kill rows, 128 bits each (2 KB)
    __shared__ unsigned char  sdead[CH];
    __shared__ unsigned short swidx[TOPK];    // winner anchor ids (rank order)
    __shared__ int            sW;

    const int blk = blockIdx.x;
    const int b   = blk / CF;
    const int c   = blk % CF + 1;
    const int t   = threadIdx.x;
    const int l   = t & 63;
    const int w   = t >> 6;                   // 0..7

    const unsigned short* const rsrc = ranks_ws + (size_t)blk * A_N;
    const uint64_t* const ioub = iou_ws + (size_t)b * A_N * IOU_WPR;
    for (int i = t; i < A_N; i += CTHREADS) sranks[i] = rsrc[i];
    if (t == 0) sW = 0;
    __syncthreads();

    int W = 0;
    for (int cb = 0; cb < A_N; cb += CH) {
        if (sranks[cb] == 0xFFFF) break;      // sorted: rest invalid (uniform)

        const unsigned short rk0 = sranks[cb + l];
        const unsigned short rk1 = sranks[cb + 64 + l];

        // P1: cross-test vs prior winners, 4 helpers per box; 1 bit load per pair
        {
            const int bx = t >> 2, q = t & 3;
            const unsigned short rkx = sranks[cb + bx];
            const bool valid = (rkx != 0xFFFF);
            const int cwi = valid ? (rkx >> 6) : 0;   // clamp: keep loads in-bounds
            const int cbi = rkx & 63;
            int dead = valid ? 0 : 1;
            #pragma unroll 4
            for (int i = q; i < W; i += 4) {          // no early exit -> loads pipeline
                const int wa = swidx[i];              // uniform LDS read
                dead |= (int)((ioub[(size_t)wa * IOU_WPR + cwi] >> cbi) & 1);
            }
            dead |= __shfl_xor(dead, 1, 64);
            dead |= __shfl_xor(dead, 2, 64);
            if (q == 0) sdead[bx] = (unsigned char)dead;
        }
        __syncthreads();

        // P2: kill rows for alive rows only; wave w owns rows [16w,16w+16);
        //     per row: 2 bit loads per lane + 2 ballots
        {
            const bool v0 = (rk0 != 0xFFFF), v1 = (rk1 != 0xFFFF);
            const int cw0 = v0 ? (rk0 >> 6) : 0, cb0 = rk0 & 63;
            const int cw1 = v1 ? (rk1 >> 6) : 0, cb1 = rk1 & 63;
            const int rbase = w * 16;
            uint32_t rm = (uint32_t)__ballot(l < 16 && !sdead[rbase + l]) & 0xFFFFu;
            while (rm) {                               // uniform per wave
                const int j = __ffs(rm) - 1; rm &= rm - 1;
                const int row = rbase + j;
                const unsigned short ra = sranks[cb + row];   // alive => valid
                const uint64_t* const rr = ioub + (size_t)ra * IOU_WPR;
                const uint64_t m0 = __ballot(((rr[cw0] >> cb0) & 1) != 0);
                const uint64_t m1 = __ballot(((rr[cw1] >> cb1) & 1) != 0);
                if (l == 0) { srow[row][0] = m0; srow[row][1] = m1; }
            }
        }
        __syncthreads();

        // P3: wave-0 scalar resolve (R8-verified): ctz + readlane + andn per winner
        if (w == 0) {
            const uint64_t r0lo = srow[l][0];        // row l
            const uint64_t r0hi = srow[l][1];
            const uint64_t r1lo = srow[64 + l][0];   // row 64+l
            const uint64_t r1hi = srow[64 + l][1];
            uint64_t alive0 = __ballot(sdead[l] == 0);
            uint64_t alive1 = __ballot(sdead[64 + l] == 0);
            int Wl = W;
            while ((alive0 | alive1) && Wl < TOPK) {
                const int f = alive0 ? __builtin_ctzll(alive0)
                                     : 64 + __builtin_ctzll(alive1);
                if (f < 64) {
                    if (l == f)      swidx[Wl] = rk0;
                } else {
                    if (l == f - 64) swidx[Wl] = rk1;
                }
                uint64_t klo, khi;
                if (f < 64) { klo = readlane_u64(r0lo, f);      khi = readlane_u64(r0hi, f); }
                else        { klo = readlane_u64(r1lo, f - 64); khi = readlane_u64(r1hi, f - 64); }
                alive0 &= ~klo;                  // winner self-clears (diag IoU = 1)
                alive1 &= ~khi;
                ++Wl;
            }
            if (l == 0) sW = Wl;
        }
        __syncthreads();
        W = sW;
        if (W >= TOPK) break;
    }

    // epilogue: reconstruct keys (bitwise == sort_kernel's) and write kept list
    const uint32_t  base = (uint32_t)(c - 1) * A_N;
    uint64_t* const out  = ws_keys + ((size_t)b * CF + (c - 1)) * TOPK;
    for (int k2 = t; k2 < TOPK; k2 += CTHREADS) {
        if (k2 < W) {
            const int a = swidx[k2];
            const float2 ms = ms_ws[(size_t)b * A_N + a];
            const float  sc = expf(scores[((size_t)b * A_N + a) * NC + c] - ms.x) / ms.y;
            out[k2] = ((uint64_t)(uint32_t)(~__float_as_uint(sc)) << 32)
                    | (uint64_t)(base + (uint32_t)a);
        } else {
            out[k2] = ~0ull;
        }
    }
}

// ---- chunk_nms (R8 kernel, verified): fallback when ws lacks the bit matrix ----
__global__ __launch_bounds__(CTHREADS)
void chunk_nms_kernel(const float* __restrict__ scores,
                      const float2* __restrict__ ms_ws,
                      const float4* __restrict__ boxes_ws,
                      const unsigned short* __restrict__ ranks_ws,
                      uint64_t* __restrict__ ws_keys)
{
    __shared__ unsigned short sranks[A_N];
    __shared__ uint64_t       srow[CH][2];
    __shared__ unsigned char  sdead[CH];
    __shared__ float4         swbox[TOPK];
    __shared__ float          swarea[TOPK];
    __shared__ unsigned short swidx[TOPK];
    __shared__ int            sW;

    const int blk = blockIdx.x;
    const int b   = blk / CF;
    const int c   = blk % CF + 1;
    const int t   = threadIdx.x;
    const int l   = t & 63;
    const int w   = t >> 6;

    const unsigned short* const rsrc = ranks_ws + (size_t)blk * A_N;
    const float4* const bbase = boxes_ws + (size_t)b * A_N;
    for (int i = t; i < A_N; i += CTHREADS) sranks[i] = rsrc[i];
    if (t == 0) sW = 0;
    __syncthreads();

    int W = 0;
    for (int cb = 0; cb < A_N; cb += CH) {
        if (sranks[cb] == 0xFFFF) break;
        const unsigned short rk0 = sranks[cb + l];
        const unsigned short rk1 = sranks[cb + 64 + l];
        const float4 box_lo = (rk0 != 0xFFFF) ? bbase[rk0] : make_float4(-8.f, -8.f, -8.f, -8.f);
        const float4 box_hi = (rk1 != 0xFFFF) ? bbase[rk1] : make_float4(-8.f, -8.f, -8.f, -8.f);
        const float  al = box_area(box_lo);
        const float  ah = box_area(box_hi);
        {
            const int bx = t >> 2, q = t & 3;
            const unsigned short rkx = sranks[cb + bx];
            const bool valid = (rkx != 0xFFFF);
            const float4 bv = valid ? bbase[rkx] : make_float4(-8.f, -8.f, -8.f, -8.f);
            const float  av = box_area(bv);
            int dead = valid ? 0 : 1;
            #pragma unroll 4
            for (int i = q; i < W; i += 4) {
                dead |= iou_gt(swbox[i], swarea[i], bv, av) ? 1 : 0;
            }
            dead |= __shfl_xor(dead, 1, 64);
            dead |= __shfl_xor(dead, 2, 64);
            if (q == 0) sdead[bx] = (unsigned char)dead;
        }
        __syncthreads();
        {
            const int rbase = w * 16;
            uint32_t rm = (uint32_t)__ballot(l < 16 && !sdead[rbase + l]) & 0xFFFFu;
            while (rm) {
                const int j = __ffs(rm) - 1; rm &= rm - 1;
                const int row = rbase + j;
                const float4 rowsrc = (row < 64) ? box_lo : box_hi;
                const float4 rbx = shfl_box(rowsrc, row & 63);
                const float  ra  = box_area(rbx);
                const uint64_t m0 = __ballot(iou_gt(rbx, ra, box_lo, al));
                const uint64_t m1 = __ballot(iou_gt(rbx, ra, box_hi, ah));
                if (l == 0) { srow[row][0] = m0; srow[row][1] = m1; }
            }
        }
        __syncthreads();
        if (w == 0) {
            const uint64_t r0lo = srow[l][0];
            const uint64_t r0hi = srow[l][1];
            const uint64_t r1lo = srow[64 + l][0];
            const uint64_t r1hi = srow[64 + l][1];
            uint64_t alive0 = __ballot(sdead[l] == 0);
            uint64_t alive1 = __ballot(sdead[64 + l] == 0);
            int Wl = W;
            while ((alive0 | alive1) && Wl < TOPK) {
                const int f = alive0 ? __builtin_ctzll(alive0)
                                     : 64 + __builtin_ctzll(alive1);
                if (f < 64) {
                    if (l == f)      { swidx[Wl] = rk0; swbox[Wl] = box_lo; swarea[Wl] = al; }
                } else {
                    if (l == f - 64) { swidx[Wl] = rk1; swbox[Wl] = box_hi; swarea[Wl] = ah; }
                }
                uint64_t klo, khi;
                if (f < 64) { klo = readlane_u64(r0lo, f);      khi = readlane_u64(r0hi, f); }
                else        { klo = readlane_u64(r1lo, f - 64); khi = readlane_u64(r1hi, f - 64); }
                alive0 &= ~klo;
                alive1 &= ~khi;
                ++Wl;
            }
            if (l == 0) sW = Wl;
        }
        __syncthreads();
        W = sW;
        if (W >= TOPK) break;
    }

    const uint32_t  base = (uint32_t)(c - 1) * A_N;
    uint64_t* const out  = ws_keys + ((size_t)b * CF + (c - 1)) * TOPK;
    for (int k2 = t; k2 < TOPK; k2 += CTHREADS) {
        if (k2 < W) {
            const int a = swidx[k2];
            const float2 ms = ms_ws[(size_t)b * A_N + a];
            const float  sc = expf(scores[((size_t)b * A_N + a) * NC + c] - ms.x) / ms.y;
            out[k2] = ((uint64_t)(uint32_t)(~__float_as_uint(sc)) << 32)
                    | (uint64_t)(base + (uint32_t)a);
        } else {
            out[k2] = ~0ull;
        }
    }
}

// ---- mono fallback (R4 kernel, verified) for small ws ----
template <bool PREP>
__global__ __launch_bounds__(THREADS)
void nms_mono(const float* __restrict__ locs,
              const float* __restrict__ scores,
              const float* __restrict__ anchors,
              const float4* __restrict__ boxes_ws,
              const float2* __restrict__ ms_ws,
              uint64_t* __restrict__ ws_keys)
{
    __shared__ uint64_t      skeys[SORT_N];
    __shared__ float4        sbox[A_N];
    __shared__ float4        schunk[CH];
    __shared__ uint64_t      srow[CH][2];
    __shared__ float4        swbox[TOPK];
    __shared__ uint64_t      swkey[TOPK];
    __shared__ unsigned char sdead[CH];
    __shared__ int           sW;

    const int blk = blockIdx.x;
    const int b   = blk / CF;
    const int c   = blk % CF + 1;
    const int t   = threadIdx.x;
    const int l   = t & 63;
    const int w   = t >> 6;

    #pragma unroll
    for (int i = 0; i < A_N / THREADS; ++i) {
        const int a = t + i * THREADS;
        float4 v; float m, sum;
        if (PREP) {
            v = boxes_ws[b * A_N + a];
            const float2 ms = ms_ws[b * A_N + a];
            m = ms.x; sum = ms.y;
        } else {
            v = decode_box(((const float4*)locs)[(size_t)b * A_N + a],
                           ((const float4*)anchors)[a]);
            const float* sp = scores + ((size_t)b * A_N + a) * NC;
            m = sp[0];
            #pragma unroll
            for (int k = 1; k < NC; ++k) m = fmaxf(m, sp[k]);
            sum = 0.0f;
            #pragma unroll
            for (int k = 0; k < NC; ++k) sum += expf(sp[k] - m);
        }
        sbox[a] = v;
        const float sl = scores[((size_t)b * A_N + a) * NC + c];
        const float sc = expf(sl - m) / sum;
        skeys[a] = (sc > 0.01f) ? pack_key(sc, (uint32_t)a) : ~0ull;
    }
    for (int i = A_N + t; i < SORT_N; i += THREADS) skeys[i] = ~0ull;
    if (t == 0) sW = 0;
    __syncthreads();

    uint64_t k[8];
    #pragma unroll
    for (int r = 0; r < 8; ++r) k[r] = skeys[(w << 9) + (r << 6) + l];
    for (int kk = 2; kk <= SORT_N; kk <<= 1) {
        for (int j = kk >> 1; j; j >>= 1) {
            if (j >= 512) {
                __syncthreads();
                #pragma unroll
                for (int r = 0; r < 8; ++r) skeys[(w << 9) + (r << 6) + l] = k[r];
                __syncthreads();
                #pragma unroll
                for (int r = 0; r < 8; ++r) {
                    const int e = (w << 9) + (r << 6) + l;
                    const uint64_t o = skeys[e ^ j];
                    const bool keep_min = (((e & j) == 0) == ((e & kk) == 0));
                    const uint64_t mn = k[r] < o ? k[r] : o;
                    const uint64_t mx = k[r] < o ? o : k[r];
                    k[r] = keep_min ? mn : mx;
                }
            } else if (j >= 64) {
                const int rb = j >> 6;
                #pragma unroll
                for (int r = 0; r < 8; ++r) {
                    if ((r & rb) == 0) {
                        const int p = r | rb;
                        const int e = (w << 9) + (r << 6) + l;
                        const bool up = ((e & kk) == 0);
                        const uint64_t x = k[r], y = k[p];
                        const uint64_t mn = x < y ? x : y;
                        const uint64_t mx = x < y ? y : x;
                        k[r] = up ? mn : mx;
                        k[p] = up ? mx : mn;
                    }
                }
            } else {
                #pragma unroll
                for (int r = 0; r < 8; ++r) {
                    const uint64_t o = (uint64_t)__shfl_xor((unsigned long long)k[r], j, 64);
                    const int e = (w << 9) + (r << 6) + l;
                    const bool keep_min = (((e & j) == 0) == ((e & kk) == 0));
                    const uint64_t mn = k[r] < o ? k[r] : o;
                    const uint64_t mx = k[r] < o ? o : k[r];
                    k[r] = keep_min ? mn : mx;
                }
            }
        }
    }
    __syncthreads();
    #pragma unroll
    for (int r = 0; r < 8; ++r) skeys[(w << 9) + (r << 6) + l] = k[r];
    __syncthreads();

    int W = 0;
    for (int cb = 0; cb < SORT_N; cb += CH) {
        if (skeys[cb] == ~0ull) break;
        if (t < CH) {
            const uint64_t kc = skeys[cb + t];
            const bool v = (kc != ~0ull);
            schunk[t] = v ? sbox[(uint32_t)kc] : make_float4(-8.f, -8.f, -8.f, -8.f);
            sdead[t]  = v ? 0 : 1;
        }
        __syncthreads();
        const float4 cb0 = schunk[l];
        const float4 cb1 = schunk[64 + l];
        const float  ca0 = box_area(cb0);
        const float  ca1 = box_area(cb1);
        for (int r = w * 32; r < w * 32 + 32; ++r) {
            const float4 rbx = schunk[r];
            const float  ra  = box_area(rbx);
            const uint64_t m0 = __ballot(iou_gt(rbx, ra, cb0, ca0));
            const uint64_t m1 = __ballot(iou_gt(rbx, ra, cb1, ca1));
            if (l == 0) { srow[r][0] = m0; srow[r][1] = m1; }
        }
        {
            const int jj = t >> 1, h = t & 1;
            const float4 bj = schunk[jj];
            const float  aj = box_area(bj);
            int sup = 0;
            for (int w2 = h; w2 < W; w2 += 2) {
                const float4 bw = swbox[w2];
                if (iou_gt(bw, box_area(bw), bj, aj)) { sup = 1; break; }
            }
            sup |= __shfl_xor(sup, 1, 64);
            if (h == 0 && sup) sdead[jj] = 1;
        }
        __syncthreads();
        if (t < 64) {
            bool al0 = !sdead[t];
            bool al1 = !sdead[64 + t];
            int Wl = W;
            while (true) {
                const unsigned long long bal0 = __ballot(al0);
                const unsigned long long bal1 = __ballot(al1);
                if (!(bal0 | bal1)) break;
                const int f = bal0 ? (__ffsll(bal0) - 1) : (64 + __ffsll(bal1) - 1);
                if (t == 0) { swkey[Wl] = skeys[cb + f]; swbox[Wl] = schunk[f]; }
                const uint64_t r0 = srow[f][0];
                const uint64_t r1 = srow[f][1];
                al0 = al0 && !((r0 >> t) & 1);
                al1 = al1 && !((r1 >> t) & 1);
                if (++Wl >= TOPK) break;
            }
            if (t == 0) sW = Wl;
        }
        __syncthreads();
        W = sW;
        if (W >= TOPK) break;
    }

    const uint32_t  base = (uint32_t)(c - 1) * A_N;
    uint64_t* const out  = ws_keys + ((size_t)b * CF + (c - 1)) * TOPK;
    for (int kx = t; kx < TOPK; kx += THREADS) {
        if (kx < W) {
            const uint64_t kk2 = swkey[kx];
            out[kx] = (kk2 & 0xFFFFFFFF00000000ull) | (uint64_t)(base + (uint32_t)kk2);
        } else {
            out[kx] = ~0ull;
        }
    }
}

// ---- merge: per batch top-200 of 20 sorted lists (R2..R8-verified) ----
__global__ __launch_bounds__(THREADS)
void merge_kernel(const float* __restrict__ locs,
                  const float* __restrict__ anchors,
                  const uint64_t* __restrict__ ws_keys,
                  float* __restrict__ out)
{
    __shared__ uint64_t Abuf[20][256];
    __shared__ uint64_t Bbuf[10][256];

    const int b = blockIdx.x;
    const int t = threadIdx.x;
    const uint64_t* const in = ws_keys + (size_t)b * CF * TOPK;

    for (int e = t; e < CF * 256; e += THREADS) {
        const int c = e >> 8, i = e & 255;
        Abuf[c][i] = (i < TOPK) ? in[c * TOPK + i] : ~0ull;
    }

    uint64_t (*src)[256] = Abuf;
    uint64_t (*dst)[256] = Bbuf;
    int n = CF;
    while (n > 1) {
        const int  nm    = n >> 1;
        const bool carry = (n & 1) != 0;
        __syncthreads();
        for (int e = t; e < nm * 256; e += THREADS) {
            const int mm = e >> 8, i = e & 255;
            const uint64_t x = src[2 * mm][i];
            const uint64_t y = src[2 * mm + 1][255 - i];
            dst[mm][i] = x < y ? x : y;
        }
        if (carry)
            for (int i = t; i < 256; i += THREADS) dst[nm][i] = src[n - 1][i];
        for (int j = 128; j; j >>= 1) {
            __syncthreads();
            for (int pp = t; pp < nm * 128; pp += THREADS) {
                const int mm = pp >> 7, qq = pp & 127;
                const int i  = ((qq & ~(j - 1)) << 1) | (qq & (j - 1));
                const uint64_t x = dst[mm][i], y = dst[mm][i + j];
                if (y < x) { dst[mm][i] = y; dst[mm][i + j] = x; }
            }
        }
        uint64_t (*tmp)[256] = src; src = dst; dst = tmp;
        n = nm + (carry ? 1 : 0);
    }
    __syncthreads();

    if (t < TOPK) {
        const uint64_t k = src[0][t];
        float* const boxes_out  = out;
        float* const labels_out = out + (size_t)B_N * TOPK * 4;
        float* const scores_out = out + (size_t)B_N * TOPK * 5;
        const size_t s = (size_t)b * TOPK + t;
        if (k == ~0ull) {
            boxes_out[s * 4 + 0] = 0.0f;
            boxes_out[s * 4 + 1] = 0.0f;
            boxes_out[s * 4 + 2] = 0.0f;
            boxes_out[s * 4 + 3] = 0.0f;
            labels_out[s] = 0.0f;
            scores_out[s] = 0.0f;
        } else {
            const uint32_t flat = (uint32_t)k;
            const int cls = flat / A_N;
            const int a   = flat - cls * A_N;
            const float sc = __uint_as_float(~(uint32_t)(k >> 32));
            const float4 v = decode_box(((const float4*)locs)[(size_t)b * A_N + a],
                                        ((const float4*)anchors)[a]);
            boxes_out[s * 4 + 0] = v.x;
            boxes_out[s * 4 + 1] = v.y;
            boxes_out[s * 4 + 2] = v.z;
            boxes_out[s * 4 + 3] = v.w;
            labels_out[s] = (float)(cls + 1);
            scores_out[s] = sc;
        }
    }
}

extern "C" void kernel_launch(void* const* d_in, const int* in_sizes, int n_in,
                              void* d_out, int out_size, void* d_ws, size_t ws_size,
                              hipStream_t stream) {
    const float* locs    = (const float*)d_in[0];
    const float* scores  = (const float*)d_in[1];
    const float* anchors = (const float*)d_in[2];
    uint64_t*       ws_keys  = (uint64_t*)d_ws;
    float4*         boxes_ws = (float4*)((char*)d_ws + BOX_OFF);
    float2*         ms_ws    = (float2*)((char*)d_ws + MS_OFF);
    unsigned short* ranks_ws = (unsigned short*)((char*)d_ws + RANKS_OFF);
    uint64_t*       iou_ws   = (uint64_t*)((char*)d_ws + IOU_OFF);
    float*          outp     = (float*)d_out;

    if (ws_size >= WS_C_BYTES) {
        hipLaunchKernelGGL(prep_kernel, dim3((B_N * A_N + THREADS - 1) / THREADS),
                           dim3(THREADS), 0, stream, locs, scores, anchors, boxes_ws, ms_ws);
        hipLaunchKernelGGL(iou_kernel, dim3(B_N * IOU_WPR * 10 / (THREADS / 64)),
                           dim3(THREADS), 0, stream, boxes_ws, iou_ws);
        hipLaunchKernelGGL(sort_kernel, dim3(B_N * CF), dim3(THREADS), 0, stream,
                           scores, ms_ws, ranks_ws);
        hipLaunchKernelGGL(chunk_nms_iou_kernel, dim3(B_N * CF), dim3(CTHREADS), 0, stream,
                           scores, ms_ws, ranks_ws, iou_ws, ws_keys);
    } else if (ws_size >= WS_A_BYTES) {
        hipLaunchKernelGGL(prep_kernel, dim3((B_N * A_N + THREADS - 1) / THREADS),
                           dim3(THREADS), 0, stream, locs, scores, anchors, boxes_ws, ms_ws);
        hipLaunchKernelGGL(sort_kernel, dim3(B_N * CF), dim3(THREADS), 0, stream,
                           scores, ms_ws, ranks_ws);
        hipLaunchKernelGGL(chunk_nms_kernel, dim3(B_N * CF), dim3(CTHREADS), 0, stream,
                           scores, ms_ws, boxes_ws, ranks_ws, ws_keys);
    } else if (ws_size >= WS_B_BYTES) {
        hipLaunchKernelGGL(prep_kernel, dim3((B_N * A_N + THREADS - 1) / THREADS),
                           dim3(THREADS), 0, stream, locs, scores, anchors, boxes_ws, ms_ws);
        hipLaunchKernelGGL((nms_mono<true>), dim3(B_N * CF), dim3(THREADS), 0, stream,
                           locs, scores, anchors, boxes_ws, ms_ws, ws_keys);
    } else {
        hipLaunchKernelGGL((nms_mono<false>), dim3(B_N * CF), dim3(THREADS), 0, stream,
                           locs, scores, anchors, boxes_ws, ms_ws, ws_keys);
    }
    hipLaunchKernelGGL(merge_kernel, dim3(B_N), dim3(THREADS), 0, stream,
                       locs, anchors, ws_keys, outp);
}

// Round 10
// 171.082 us; speedup vs baseline: 1.4137x; 1.4137x over previous
//
#include <hip/hip_runtime.h>
#include <stdint.h>

// DetectionBaseline: SSD post-process. R10: sort FUSED into the NMS kernel (same
// per-(b,c) block decomposition) — removes the sort dispatch, the u16 ranks global
// round-trip, and one barrier-heavy staging pass. Chunk body = R8's verified
// on-the-fly-IoU 3-phase loop (bit-matrix variant of R9 regressed; reverted).
//   prep      : per (b,a) box decode + softmax (m,sum)   [batch-shared]
//   fused_nms : per (b,c): key build -> register bitonic sort -> chunked greedy NMS
//   merge     : per b truncated pairwise bitonic merges -> top-200 output

#define A_N     1280
#define CF      20
#define NC      21
#define B_N     16
#define TOPK    200
#define THREADS 256
#define CTHREADS 512
#define SORT_N  2048
#define CH      128

// ws layout (bytes)
#define KEYS_BYTES   (B_N * CF * TOPK * 8)                 // 512000 kept-key lists
#define BOX_OFF      KEYS_BYTES                             // float4 [16*1280] = 327680
#define MS_OFF       (BOX_OFF + B_N * A_N * 16)             // float2 [16*1280] = 163840
#define WS_B_BYTES   (MS_OFF + B_N * A_N * 8)               // 1003520 (fused tier)

static __device__ __forceinline__ uint64_t pack_key(float sc, uint32_t idx) {
    // softmax scores positive -> float bits monotone. ~bits => ascending key = descending
    // score; low 32 bits = index => ties break toward smaller index (stable argsort / top_k).
    return ((uint64_t)(uint32_t)(~__float_as_uint(sc)) << 32) | (uint64_t)idx;
}

static __device__ __forceinline__ float box_area(const float4 v) {
    return (v.z - v.x) * (v.w - v.y);
}

static __device__ __forceinline__ bool iou_gt(const float4 a, const float aarea,
                                              const float4 b, const float barea) {
    // ref-exact: inter/(area_a + area_b - inter) > 0.45; exactly symmetric in IEEE
    const float lx = fmaxf(a.x, b.x);
    const float ly = fmaxf(a.y, b.y);
    const float rx = fminf(a.z, b.z);
    const float ry = fminf(a.w, b.w);
    const float wx = fmaxf(rx - lx, 0.0f);
    const float wy = fmaxf(ry - ly, 0.0f);
    const float inter = wx * wy;
    const float uni   = aarea + barea - inter;
    return inter / uni > 0.45f;
}

static __device__ __forceinline__ float4 decode_box(const float4 lc, const float4 an) {
    const float cx = lc.x * an.z / 10.0f + an.x;
    const float cy = lc.y * an.w / 10.0f + an.y;
    const float w  = expf(lc.z / 5.0f) * an.z;
    const float h  = expf(lc.w / 5.0f) * an.w;
    float4 v;
    v.x = cx - w / 2.0f; v.y = cy - h / 2.0f;
    v.z = cx + w / 2.0f; v.w = cy + h / 2.0f;
    return v;
}

static __device__ __forceinline__ float4 shfl_box(const float4 v, int lane) {
    float4 r;
    r.x = __shfl(v.x, lane, 64);
    r.y = __shfl(v.y, lane, 64);
    r.z = __shfl(v.z, lane, 64);
    r.w = __shfl(v.w, lane, 64);
    return r;
}

static __device__ __forceinline__ uint64_t readlane_u64(uint64_t v, int lane) {
    const uint32_t lo = (uint32_t)__builtin_amdgcn_readlane((int)(uint32_t)v, lane);
    const uint32_t hi = (uint32_t)__builtin_amdgcn_readlane((int)(uint32_t)(v >> 32), lane);
    return ((uint64_t)hi << 32) | lo;
}

// ---- prep: per (b,a) decoded box + softmax (max, sum) ----
__global__ __launch_bounds__(THREADS)
void prep_kernel(const float* __restrict__ locs,
                 const float* __restrict__ scores,
                 const float* __restrict__ anchors,
                 float4* __restrict__ boxes_ws,
                 float2* __restrict__ ms_ws)
{
    const int g = blockIdx.x * THREADS + threadIdx.x;
    if (g >= B_N * A_N) return;
    const int a = g % A_N;
    boxes_ws[g] = decode_box(((const float4*)locs)[g], ((const float4*)anchors)[a]);
    const float* sp = scores + (size_t)g * NC;
    float m = sp[0];
    #pragma unroll
    for (int k = 1; k < NC; ++k) m = fmaxf(m, sp[k]);
    float sum = 0.0f;
    #pragma unroll
    for (int k = 0; k < NC; ++k) sum += expf(sp[k] - m);
    ms_ws[g] = make_float2(m, sum);
}

// ---- fused_nms (512 threads): key build + register bitonic sort + chunked NMS ----
__global__ __launch_bounds__(CTHREADS)
void fused_nms_kernel(const float* __restrict__ scores,
                      const float2* __restrict__ ms_ws,
                      const float4* __restrict__ boxes_ws,
                      uint64_t* __restrict__ ws_keys)
{
    __shared__ uint64_t      skeys[SORT_N];   // 16 KB sorted keys
    __shared__ uint64_t      srow[CH][2];     // kill rows, 128 bits each
    __shared__ unsigned char sdead[CH];
    __shared__ float4        swbox[TOPK];     // winner boxes (cross-test)
    __shared__ float         swarea[TOPK];    // winner areas
    __shared__ uint64_t      swkey[TOPK];     // winner sorted keys (rank order)
    __shared__ int           sW;

    const int blk = blockIdx.x;
    const int b   = blk / CF;
    const int c   = blk % CF + 1;             // class channel 1..20
    const int t   = threadIdx.x;              // 0..511
    const int l   = t & 63;
    const int w   = t >> 6;                   // 0..7

    // ---- key build (ref-exact softmax from prep's m,sum) ----
    #pragma unroll
    for (int i = 0; i < SORT_N / CTHREADS; ++i) {
        const int a = t + i * CTHREADS;
        if (a < A_N) {
            const float2 ms = ms_ws[b * A_N + a];
            const float  sl = scores[((size_t)b * A_N + a) * NC + c];
            const float  sc = expf(sl - ms.x) / ms.y;
            skeys[a] = (sc > 0.01f) ? pack_key(sc, (uint32_t)a) : ~0ull;
        } else {
            skeys[a] = ~0ull;
        }
    }
    if (t == 0) sW = 0;
    __syncthreads();

    // ---- register/wave bitonic sort: 4 keys/thread, e = (w<<8)|(r<<6)|l ----
    uint64_t k[4];
    #pragma unroll
    for (int r = 0; r < 4; ++r) k[r] = skeys[(w << 8) + (r << 6) + l];

    for (int kk = 2; kk <= SORT_N; kk <<= 1) {
        for (int j = kk >> 1; j; j >>= 1) {
            if (j >= 256) {
                // cross-wave: LDS round trip
                __syncthreads();
                #pragma unroll
                for (int r = 0; r < 4; ++r) skeys[(w << 8) + (r << 6) + l] = k[r];
                __syncthreads();
                #pragma unroll
                for (int r = 0; r < 4; ++r) {
                    const int e = (w << 8) + (r << 6) + l;
                    const uint64_t o = skeys[e ^ j];
                    const bool keep_min = (((e & j) == 0) == ((e & kk) == 0));
                    const uint64_t mn = k[r] < o ? k[r] : o;
                    const uint64_t mx = k[r] < o ? o : k[r];
                    k[r] = keep_min ? mn : mx;
                }
            } else if (j >= 64) {
                // in-thread register exchange
                const int rb = j >> 6;                 // 1 or 2
                #pragma unroll
                for (int r = 0; r < 4; ++r) {
                    if ((r & rb) == 0) {
                        const int p = r | rb;
                        const int e = (w << 8) + (r << 6) + l;
                        const bool up = ((e & kk) == 0);
                        const uint64_t x = k[r], y = k[p];
                        const uint64_t mn = x < y ? x : y;
                        const uint64_t mx = x < y ? y : x;
                        k[r] = up ? mn : mx;
                        k[p] = up ? mx : mn;
                    }
                }
            } else {
                // in-wave shuffle exchange
                #pragma unroll
                for (int r = 0; r < 4; ++r) {
                    const uint64_t o = (uint64_t)__shfl_xor((unsigned long long)k[r], j, 64);
                    const int e = (w << 8) + (r << 6) + l;
                    const bool keep_min = (((e & j) == 0) == ((e & kk) == 0));
                    const uint64_t mn = k[r] < o ? k[r] : o;
                    const uint64_t mx = k[r] < o ? o : k[r];
                    k[r] = keep_min ? mn : mx;
                }
            }
        }
    }
    __syncthreads();   // last LDS-pass readers done before overwrite
    #pragma unroll
    for (int r = 0; r < 4; ++r) skeys[(w << 8) + (r << 6) + l] = k[r];
    __syncthreads();

    // ---- chunked greedy NMS (R8-verified body, keys straight from LDS) ----
    const float4* const bbase = boxes_ws + (size_t)b * A_N;
    int W = 0;
    for (int cb = 0; cb < A_N; cb += CH) {
        if (skeys[cb] == ~0ull) break;        // sorted: rest invalid (uniform)

        // column boxes: lane l holds cols l and 64+l (L2-hot loads)
        const uint64_t key0 = skeys[cb + l];
        const uint64_t key1 = skeys[cb + 64 + l];
        const bool v0 = (key0 != ~0ull), v1 = (key1 != ~0ull);
        const float4 box_lo = v0 ? bbase[(uint32_t)key0] : make_float4(-8.f, -8.f, -8.f, -8.f);
        const float4 box_hi = v1 ? bbase[(uint32_t)key1] : make_float4(-8.f, -8.f, -8.f, -8.f);
        const float  al = box_area(box_lo);
        const float  ah = box_area(box_hi);

        // P1: cross-test vs prior winners, 4 helpers per box (pipelined, no early exit)
        {
            const int bx = t >> 2, q = t & 3;
            const uint64_t keyx = skeys[cb + bx];
            const bool valid = (keyx != ~0ull);
            const float4 bv = valid ? bbase[(uint32_t)keyx] : make_float4(-8.f, -8.f, -8.f, -8.f);
            const float  av = box_area(bv);
            int dead = valid ? 0 : 1;
            #pragma unroll 4
            for (int i = q; i < W; i += 4) {
                dead |= iou_gt(swbox[i], swarea[i], bv, av) ? 1 : 0;
            }
            dead |= __shfl_xor(dead, 1, 64);
            dead |= __shfl_xor(dead, 2, 64);
            if (q == 0) sdead[bx] = (unsigned char)dead;
        }
        __syncthreads();

        // P2: sparse alive-row kill-matrix build; wave w owns rows [16w,16w+16)
        {
            const int rbase = w * 16;
            uint32_t rm = (uint32_t)__ballot(l < 16 && !sdead[rbase + l]) & 0xFFFFu;
            while (rm) {                          // uniform per wave (ballot result)
                const int j = __ffs(rm) - 1; rm &= rm - 1;
                const int row = rbase + j;
                const float4 rowsrc = (row < 64) ? box_lo : box_hi;
                const float4 rbx = shfl_box(rowsrc, row & 63);
                const float  ra  = box_area(rbx);
                const uint64_t m0 = __ballot(iou_gt(rbx, ra, box_lo, al));
                const uint64_t m1 = __ballot(iou_gt(rbx, ra, box_hi, ah));
                if (l == 0) { srow[row][0] = m0; srow[row][1] = m1; }
            }
        }
        __syncthreads();

        // P3: wave-0 scalar resolve: ctz + readlane + andn per winner (R8-verified)
        if (w == 0) {
            const uint64_t r0lo = srow[l][0];        // row l
            const uint64_t r0hi = srow[l][1];
            const uint64_t r1lo = srow[64 + l][0];   // row 64+l
            const uint64_t r1hi = srow[64 + l][1];
            uint64_t alive0 = __ballot(sdead[l] == 0);
            uint64_t alive1 = __ballot(sdead[64 + l] == 0);
            int Wl = W;
            while ((alive0 | alive1) && Wl < TOPK) {
                const int f = alive0 ? __builtin_ctzll(alive0)
                                     : 64 + __builtin_ctzll(alive1);
                if (f < 64) {
                    if (l == f)      { swkey[Wl] = key0; swbox[Wl] = box_lo; swarea[Wl] = al; }
                } else {
                    if (l == f - 64) { swkey[Wl] = key1; swbox[Wl] = box_hi; swarea[Wl] = ah; }
                }
                uint64_t klo, khi;
                if (f < 64) { klo = readlane_u64(r0lo, f);      khi = readlane_u64(r0hi, f); }
                else        { klo = readlane_u64(r1lo, f - 64); khi = readlane_u64(r1hi, f - 64); }
                alive0 &= ~klo;                  // winner self-clears (diag IoU = 1)
                alive1 &= ~khi;
                ++Wl;
            }
            if (l == 0) sW = Wl;
        }
        __syncthreads();
        W = sW;
        if (W >= TOPK) break;
    }

    // epilogue: winners already hold their sorted keys; add class base to index
    const uint32_t  base = (uint32_t)(c - 1) * A_N;
    uint64_t* const out  = ws_keys + ((size_t)b * CF + (c - 1)) * TOPK;
    for (int k2 = t; k2 < TOPK; k2 += CTHREADS) {
        if (k2 < W) {
            const uint64_t kk2 = swkey[k2];
            out[k2] = (kk2 & 0xFFFFFFFF00000000ull) | (uint64_t)(base + (uint32_t)kk2);
        } else {
            out[k2] = ~0ull;
        }
    }
}

// ---- mono fallback (R4 kernel, verified) for tiny ws ----
__global__ __launch_bounds__(THREADS)
void nms_mono(const float* __restrict__ locs,
              const float* __restrict__ scores,
              const float* __restrict__ anchors,
              uint64_t* __restrict__ ws_keys)
{
    __shared__ uint64_t      skeys[SORT_N];
    __shared__ float4        sbox[A_N];
    __shared__ float4        schunk[CH];
    __shared__ uint64_t      srow[CH][2];
    __shared__ float4        swbox[TOPK];
    __shared__ uint64_t      swkey[TOPK];
    __shared__ unsigned char sdead[CH];
    __shared__ int           sW;

    const int blk = blockIdx.x;
    const int b   = blk / CF;
    const int c   = blk % CF + 1;
    const int t   = threadIdx.x;
    const int l   = t & 63;
    const int w   = t >> 6;

    #pragma unroll
    for (int i = 0; i < A_N / THREADS; ++i) {
        const int a = t + i * THREADS;
        const float4 v = decode_box(((const float4*)locs)[(size_t)b * A_N + a],
                                    ((const float4*)anchors)[a]);
        const float* sp = scores + ((size_t)b * A_N + a) * NC;
        float m = sp[0];
        #pragma unroll
        for (int kq = 1; kq < NC; ++kq) m = fmaxf(m, sp[kq]);
        float sum = 0.0f;
        #pragma unroll
        for (int kq = 0; kq < NC; ++kq) sum += expf(sp[kq] - m);
        sbox[a] = v;
        const float sc = expf(sp[c] - m) / sum;
        skeys[a] = (sc > 0.01f) ? pack_key(sc, (uint32_t)a) : ~0ull;
    }
    for (int i = A_N + t; i < SORT_N; i += THREADS) skeys[i] = ~0ull;
    if (t == 0) sW = 0;
    __syncthreads();

    uint64_t k[8];
    #pragma unroll
    for (int r = 0; r < 8; ++r) k[r] = skeys[(w << 9) + (r << 6) + l];
    for (int kk = 2; kk <= SORT_N; kk <<= 1) {
        for (int j = kk >> 1; j; j >>= 1) {
            if (j >= 512) {
                __syncthreads();
                #pragma unroll
                for (int r = 0; r < 8; ++r) skeys[(w << 9) + (r << 6) + l] = k[r];
                __syncthreads();
                #pragma unroll
                for (int r = 0; r < 8; ++r) {
                    const int e = (w << 9) + (r << 6) + l;
                    const uint64_t o = skeys[e ^ j];
                    const bool keep_min = (((e & j) == 0) == ((e & kk) == 0));
                    const uint64_t mn = k[r] < o ? k[r] : o;
                    const uint64_t mx = k[r] < o ? o : k[r];
                    k[r] = keep_min ? mn : mx;
                }
            } else if (j >= 64) {
                const int rb = j >> 6;
                #pragma unroll
                for (int r = 0; r < 8; ++r) {
                    if ((r & rb) == 0) {
                        const int p = r | rb;
                        const int e = (w << 9) + (r << 6) + l;
                        const bool up = ((e & kk) == 0);
                        const uint64_t x = k[r], y = k[p];
                        const uint64_t mn = x < y ? x : y;
                        const uint64_t mx = x < y ? y : x;
                        k[r] = up ? mn : mx;
                        k[p] = up ? mx : mn;
                    }
                }
            } else {
                #pragma unroll
                for (int r = 0; r < 8; ++r) {
                    const uint64_t o = (uint64_t)__shfl_xor((unsigned long long)k[r], j, 64);
                    const int e = (w << 9) + (r << 6) + l;
                    const bool keep_min = (((e & j) == 0) == ((e & kk) == 0));
                    const uint64_t mn = k[r] < o ? k[r] : o;
                    const uint64_t mx = k[r] < o ? o : k[r];
                    k[r] = keep_min ? mn : mx;
                }
            }
        }
    }
    __syncthreads();
    #pragma unroll
    for (int r = 0; r < 8; ++r) skeys[(w << 9) + (r << 6) + l] = k[r];
    __syncthreads();

    int W = 0;
    for (int cb = 0; cb < SORT_N; cb += CH) {
        if (skeys[cb] == ~0ull) break;
        if (t < CH) {
            const uint64_t kc = skeys[cb + t];
            const bool v = (kc != ~0ull);
            schunk[t] = v ? sbox[(uint32_t)kc] : make_float4(-8.f, -8.f, -8.f, -8.f);
            sdead[t]  = v ? 0 : 1;
        }
        __syncthreads();
        const float4 cb0 = schunk[l];
        const float4 cb1 = schunk[64 + l];
        const float  ca0 = box_area(cb0);
        const float  ca1 = box_area(cb1);
        for (int r = w * 32; r < w * 32 + 32; ++r) {
            const float4 rbx = schunk[r];
            const float  ra  = box_area(rbx);
            const uint64_t m0 = __ballot(iou_gt(rbx, ra, cb0, ca0));
            const uint64_t m1 = __ballot(iou_gt(rbx, ra, cb1, ca1));
            if (l == 0) { srow[r][0] = m0; srow[r][1] = m1; }
        }
        {
            const int jj = t >> 1, h = t & 1;
            const float4 bj = schunk[jj];
            const float  aj = box_area(bj);
            int sup = 0;
            for (int w2 = h; w2 < W; w2 += 2) {
                const float4 bw = swbox[w2];
                if (iou_gt(bw, box_area(bw), bj, aj)) { sup = 1; break; }
            }
            sup |= __shfl_xor(sup, 1, 64);
            if (h == 0 && sup) sdead[jj] = 1;
        }
        __syncthreads();
        if (t < 64) {
            bool al0 = !sdead[t];
            bool al1 = !sdead[64 + t];
            int Wl = W;
            while (true) {
                const unsigned long long bal0 = __ballot(al0);
                const unsigned long long bal1 = __ballot(al1);
                if (!(bal0 | bal1)) break;
                const int f = bal0 ? (__ffsll(bal0) - 1) : (64 + __ffsll(bal1) - 1);
                if (t == 0) { swkey[Wl] = skeys[cb + f]; swbox[Wl] = schunk[f]; }
                const uint64_t r0 = srow[f][0];
                const uint64_t r1 = srow[f][1];
                al0 = al0 && !((r0 >> t) & 1);
                al1 = al1 && !((r1 >> t) & 1);
                if (++Wl >= TOPK) break;
            }
            if (t == 0) sW = Wl;
        }
        __syncthreads();
        W = sW;
        if (W >= TOPK) break;
    }

    const uint32_t  base = (uint32_t)(c - 1) * A_N;
    uint64_t* const out  = ws_keys + ((size_t)b * CF + (c - 1)) * TOPK;
    for (int kx = t; kx < TOPK; kx += THREADS) {
        if (kx < W) {
            const uint64_t kk2 = swkey[kx];
            out[kx] = (kk2 & 0xFFFFFFFF00000000ull) | (uint64_t)(base + (uint32_t)kk2);
        } else {
            out[kx] = ~0ull;
        }
    }
}

// ---- merge: per batch top-200 of 20 sorted lists (R2..R9-verified) ----
__global__ __launch_bounds__(THREADS)
void merge_kernel(const float* __restrict__ locs,
                  const float* __restrict__ anchors,
                  const uint64_t* __restrict__ ws_keys,
                  float* __restrict__ out)
{
    __shared__ uint64_t Abuf[20][256];
    __shared__ uint64_t Bbuf[10][256];

    const int b = blockIdx.x;
    const int t = threadIdx.x;
    const uint64_t* const in = ws_keys + (size_t)b * CF * TOPK;

    for (int e = t; e < CF * 256; e += THREADS) {
        const int c = e >> 8, i = e & 255;
        Abuf[c][i] = (i < TOPK) ? in[c * TOPK + i] : ~0ull;
    }

    uint64_t (*src)[256] = Abuf;
    uint64_t (*dst)[256] = Bbuf;
    int n = CF;
    while (n > 1) {
        const int  nm    = n >> 1;
        const bool carry = (n & 1) != 0;
        __syncthreads();
        for (int e = t; e < nm * 256; e += THREADS) {
            const int mm = e >> 8, i = e & 255;
            const uint64_t x = src[2 * mm][i];
            const uint64_t y = src[2 * mm + 1][255 - i];
            dst[mm][i] = x < y ? x : y;              // lower-half extraction (bitonic)
        }
        if (carry)
            for (int i = t; i < 256; i += THREADS) dst[nm][i] = src[n - 1][i];
        for (int j = 128; j; j >>= 1) {
            __syncthreads();
            for (int pp = t; pp < nm * 128; pp += THREADS) {
                const int mm = pp >> 7, qq = pp & 127;
                const int i  = ((qq & ~(j - 1)) << 1) | (qq & (j - 1));
                const uint64_t x = dst[mm][i], y = dst[mm][i + j];
                if (y < x) { dst[mm][i] = y; dst[mm][i + j] = x; }
            }
        }
        uint64_t (*tmp)[256] = src; src = dst; dst = tmp;
        n = nm + (carry ? 1 : 0);
    }
    __syncthreads();

    if (t < TOPK) {
        const uint64_t k = src[0][t];
        float* const boxes_out  = out;                           // [B][TOPK][4]
        float* const labels_out = out + (size_t)B_N * TOPK * 4;  // [B][TOPK]
        float* const scores_out = out + (size_t)B_N * TOPK * 5;  // [B][TOPK]
        const size_t s = (size_t)b * TOPK + t;
        if (k == ~0ull) {
            boxes_out[s * 4 + 0] = 0.0f;
            boxes_out[s * 4 + 1] = 0.0f;
            boxes_out[s * 4 + 2] = 0.0f;
            boxes_out[s * 4 + 3] = 0.0f;
            labels_out[s] = 0.0f;
            scores_out[s] = 0.0f;
        } else {
            const uint32_t flat = (uint32_t)k;
            const int cls = flat / A_N;          // 0..19
            const int a   = flat - cls * A_N;
            const float sc = __uint_as_float(~(uint32_t)(k >> 32));
            const float4 v = decode_box(((const float4*)locs)[(size_t)b * A_N + a],
                                        ((const float4*)anchors)[a]);
            boxes_out[s * 4 + 0] = v.x;
            boxes_out[s * 4 + 1] = v.y;
            boxes_out[s * 4 + 2] = v.z;
            boxes_out[s * 4 + 3] = v.w;
            labels_out[s] = (float)(cls + 1);
            scores_out[s] = sc;
        }
    }
}

extern "C" void kernel_launch(void* const* d_in, const int* in_sizes, int n_in,
                              void* d_out, int out_size, void* d_ws, size_t ws_size,
                              hipStream_t stream) {
    const float* locs    = (const float*)d_in[0];
    const float* scores  = (const float*)d_in[1];
    const float* anchors = (const float*)d_in[2];
    uint64_t* ws_keys  = (uint64_t*)d_ws;
    float4*   boxes_ws = (float4*)((char*)d_ws + BOX_OFF);
    float2*   ms_ws    = (float2*)((char*)d_ws + MS_OFF);
    float*    outp     = (float*)d_out;

    if (ws_size >= (size_t)WS_B_BYTES) {
        hipLaunchKernelGGL(prep_kernel, dim3((B_N * A_N + THREADS - 1) / THREADS),
                           dim3(THREADS), 0, stream, locs, scores, anchors, boxes_ws, ms_ws);
        hipLaunchKernelGGL(fused_nms_kernel, dim3(B_N * CF), dim3(CTHREADS), 0, stream,
                           scores, ms_ws, boxes_ws, ws_keys);
    } else {
        hipLaunchKernelGGL(nms_mono, dim3(B_N * CF), dim3(THREADS), 0, stream,
                           locs, scores, anchors, ws_keys);
    }
    hipLaunchKernelGGL(merge_kernel, dim3(B_N), dim3(THREADS), 0, stream,
                       locs, anchors, ws_keys, outp);
}